// Round 11
// baseline (700.101 us; speedup 1.0000x reference)
//
#include <hip/hip_runtime.h>
#include <hip/hip_bf16.h>

// Round 11: R10 base + (a) V^T fused into QKV epilogue via swizzled LDS transpose
// (trans_b2b deleted), (b) FFN1 -> <1,2> tile @1024 blocks (4/CU exact).

constexpr int S_ = 2048;
constexpr int E_ = 1024;
constexpr int H_ = 16;
constexpr int HS_ = 64;
constexpr int L_ = 2;
constexpr int FF_ = 4096;

typedef __bf16 bf16;
typedef __bf16 bf16x8 __attribute__((ext_vector_type(8)));
typedef __bf16 bf16x4 __attribute__((ext_vector_type(4)));
typedef float f32x4 __attribute__((ext_vector_type(4)));

__device__ __forceinline__ void gld16(const void* g, const void* l) {
  __builtin_amdgcn_global_load_lds(
      (const __attribute__((address_space(1))) unsigned int*)g,
      (__attribute__((address_space(3))) unsigned int*)l, 16, 0, 0);
}

// ---------------- embedding + first layernorm fused ----------------
__global__ __launch_bounds__(256) void embed_ln_k(const int* __restrict__ seq,
                                                  const float* __restrict__ tok,
                                                  const float* __restrict__ pos,
                                                  const float* __restrict__ gw,
                                                  const float* __restrict__ bw,
                                                  float* __restrict__ x,
                                                  bf16* __restrict__ xb) {
  __shared__ float red[8];
  const int row = blockIdx.x, tid = threadIdx.x;
  const int t = seq[row];
  float4 v = ((const float4*)(tok + (long)t * E_))[tid];
  float4 p = ((const float4*)(pos + (long)row * E_))[tid];
  v.x += p.x; v.y += p.y; v.z += p.z; v.w += p.w;
  float s = v.x + v.y + v.z + v.w;
  float ss = v.x * v.x + v.y * v.y + v.z * v.z + v.w * v.w;
  for (int off = 32; off; off >>= 1) {
    s += __shfl_down(s, off);
    ss += __shfl_down(ss, off);
  }
  if ((tid & 63) == 0) { red[(tid >> 6) * 2] = s; red[(tid >> 6) * 2 + 1] = ss; }
  __syncthreads();
  if (tid == 0) {
    float S0 = 0, SS = 0;
    for (int i = 0; i < 4; ++i) { S0 += red[i * 2]; SS += red[i * 2 + 1]; }
    red[0] = S0; red[1] = SS;
  }
  __syncthreads();
  const float mu = red[0] * (1.f / E_);
  const float var = red[1] * (1.f / E_) - mu * mu;
  const float rs = rsqrtf(var + 1e-5f);
  float4 gv = ((const float4*)gw)[tid], bv = ((const float4*)bw)[tid];
  float4 o;
  o.x = (v.x - mu) * rs * gv.x + bv.x;
  o.y = (v.y - mu) * rs * gv.y + bv.y;
  o.z = (v.z - mu) * rs * gv.z + bv.z;
  o.w = (v.w - mu) * rs * gv.w + bv.w;
  ((float4*)(x + (long)row * E_))[tid] = o;
  bf16x4 ob;
  ob[0] = (__bf16)o.x; ob[1] = (__bf16)o.y; ob[2] = (__bf16)o.z; ob[3] = (__bf16)o.w;
  ((bf16x4*)(xb + (long)row * E_))[tid] = ob;
}

// ---------------- layernorm (in-place f32) + bf16 shadow ----------------
__global__ __launch_bounds__(256) void layernorm_k(float* __restrict__ x,
                                                   const float* __restrict__ gw,
                                                   const float* __restrict__ bw,
                                                   bf16* __restrict__ xb) {
  __shared__ float red[8];
  const int row = blockIdx.x, tid = threadIdx.x;
  float4 v = ((const float4*)(x + (long)row * E_))[tid];
  float s = v.x + v.y + v.z + v.w;
  float ss = v.x * v.x + v.y * v.y + v.z * v.z + v.w * v.w;
  for (int off = 32; off; off >>= 1) {
    s += __shfl_down(s, off);
    ss += __shfl_down(ss, off);
  }
  if ((tid & 63) == 0) { red[(tid >> 6) * 2] = s; red[(tid >> 6) * 2 + 1] = ss; }
  __syncthreads();
  if (tid == 0) {
    float S0 = 0, SS = 0;
    for (int i = 0; i < 4; ++i) { S0 += red[i * 2]; SS += red[i * 2 + 1]; }
    red[0] = S0; red[1] = SS;
  }
  __syncthreads();
  const float mu = red[0] * (1.f / E_);
  const float var = red[1] * (1.f / E_) - mu * mu;
  const float rs = rsqrtf(var + 1e-5f);
  float4 gv = ((const float4*)gw)[tid], bv = ((const float4*)bw)[tid];
  float4 o;
  o.x = (v.x - mu) * rs * gv.x + bv.x;
  o.y = (v.y - mu) * rs * gv.y + bv.y;
  o.z = (v.z - mu) * rs * gv.z + bv.z;
  o.w = (v.w - mu) * rs * gv.w + bv.w;
  ((float4*)(x + (long)row * E_))[tid] = o;
  bf16x4 ob;
  ob[0] = (__bf16)o.x; ob[1] = (__bf16)o.y; ob[2] = (__bf16)o.z; ob[3] = (__bf16)o.w;
  ((bf16x4*)(xb + (long)row * E_))[tid] = ob;
}

// ---------------- unified weight repack for one layer ----------------
__global__ __launch_bounds__(256) void repack_k(const float* __restrict__ wq,
                                                const float* __restrict__ wk,
                                                const float* __restrict__ wv,
                                                const float* __restrict__ wr,
                                                const float* __restrict__ w1,
                                                const float* __restrict__ w2,
                                                bf16* __restrict__ qkvT,
                                                bf16* __restrict__ wrT,
                                                bf16* __restrict__ w1T,
                                                bf16* __restrict__ w2T) {
  __shared__ float t[32][33];
  const int tx = threadIdx.x, ty = threadIdx.y;
  const int bid = blockIdx.x;
  const float* src;
  bf16* dst;
  long ld_in, ld_out, r0, c0;
  if (bid < 3072) {
    const int j = bid >> 10;
    const int z = (bid & 1023) >> 6;
    const int rem = bid & 63;
    r0 = (rem >> 1) * 32;
    c0 = (rem & 1) * 32;
    const float* w = j == 0 ? wq : (j == 1 ? wk : wv);
    src = w + (long)z * E_ * HS_;
    dst = qkvT + (long)j * E_ * E_ + (long)z * HS_ * E_;
    ld_in = HS_; ld_out = E_;
  } else if (bid < 4096) {
    const int idx = bid - 3072;
    r0 = (idx >> 5) * 32; c0 = (idx & 31) * 32;
    src = wr; dst = wrT; ld_in = E_; ld_out = E_;
  } else if (bid < 8192) {
    const int idx = bid - 4096;
    r0 = (idx >> 7) * 32; c0 = (idx & 127) * 32;
    src = w1; dst = w1T; ld_in = FF_; ld_out = E_;
  } else {
    const int idx = bid - 8192;
    r0 = (idx >> 5) * 32; c0 = (idx & 31) * 32;
    src = w2; dst = w2T; ld_in = E_; ld_out = FF_;
  }
#pragma unroll
  for (int i = 0; i < 4; ++i)
    t[ty + 8 * i][tx] = src[(r0 + ty + 8 * i) * ld_in + c0 + tx];
  __syncthreads();
#pragma unroll
  for (int i = 0; i < 4; ++i)
    dst[(c0 + ty + 8 * i) * ld_out + r0 + tx] = (__bf16)t[tx][ty + 8 * i];
}

// ---------------- 3-buffer counted-vmcnt NT GEMM (shared staging, barrier) ----------------
// Optional Vt mode: blocks whose n-range is >= vthresh write a TRANSPOSED bf16
// tile into Vt instead of Cb, via a swizzled LDS roundtrip (coalesced 128B rows).
template <int WM, int WN>
__global__ __launch_bounds__(WM * WN * 64) void gemm_lds(
    const bf16* __restrict__ A, const bf16* __restrict__ B,
    long lda, long ldb, int K, int mtiles, float scale,
    const float* __restrict__ bias, const float* __restrict__ resid, int relu,
    float* __restrict__ Cf, long ldc, bf16* __restrict__ Cb, long ldcb,
    bf16* __restrict__ Vt, long vthresh) {
  constexpr int BM = WM * 64, BN = WN * 64, NW = WM * WN;
  constexpr int ABYTES = BM * 64;
  constexpr int BUFB = ABYTES + BN * 64;
  constexpr int NCH = BUFB / 1024;
  constexpr int CPT = NCH / NW;
  static_assert(CPT == 4 || CPT == 6, "unexpected CPT");
  __shared__ char smem[3 * BUFB];

  const int tid = threadIdx.x, wid = tid >> 6, lane = tid & 63;
  const int cpx = gridDim.x >> 3;
  const int bid = blockIdx.x;
  const int wg = (bid & 7) * cpx + (bid >> 3);
  const long m0 = (long)(wg % mtiles) * BM;
  const long n0 = (long)(wg / mtiles) * BN;

  const char* gsrc[CPT];
  int ldsbase[CPT];
#pragma unroll
  for (int i = 0; i < CPT; ++i) {
    const int c = wid + i * NW;
    const int s = c * 1024 + lane * 16;
    const bf16* base;
    int kb;
    if (s < ABYTES) {
      const int row = s >> 6;
      kb = (s ^ ((row & 3) << 4)) & 63;
      base = A + (m0 + row) * lda;
    } else {
      const int s2 = s - ABYTES;
      const int row = s2 >> 6;
      kb = (s2 ^ ((row & 3) << 4)) & 63;
      base = B + (n0 + row) * ldb;
    }
    gsrc[i] = (const char*)base + kb;
    ldsbase[i] = c * 1024;
  }

  const int fr = lane & 15, fg = lane >> 4;
  const int wm = wid % WM, wn = wid / WM;
  int aoff[4], boff[4];
#pragma unroll
  for (int t = 0; t < 4; ++t) {
    const int m = wm * 64 + t * 16 + fr;
    aoff[t] = m * 64 + ((16 * fg) ^ ((m & 3) << 4));
    const int n = wn * 64 + t * 16 + fr;
    boff[t] = ABYTES + n * 64 + ((16 * fg) ^ ((n & 3) << 4));
  }

  f32x4 acc[4][4];
#pragma unroll
  for (int i = 0; i < 4; ++i)
#pragma unroll
    for (int j = 0; j < 4; ++j) acc[i][j] = (f32x4){0.f, 0.f, 0.f, 0.f};

  const int nt = K >> 5;

  auto stage = [&](int tile, int buf) {
    const long koff = (long)tile * 64;
#pragma unroll
    for (int i = 0; i < CPT; ++i)
      gld16(gsrc[i] + koff, smem + buf * BUFB + ldsbase[i]);
  };

  stage(0, 0);
  stage(1, 1);

  int cur = 0;
  for (int t = 0; t < nt; ++t) {
    if (t < nt - 1) {
      if constexpr (CPT == 4) asm volatile("s_waitcnt vmcnt(4)" ::: "memory");
      else asm volatile("s_waitcnt vmcnt(6)" ::: "memory");
    } else {
      asm volatile("s_waitcnt vmcnt(0)" ::: "memory");
    }
    __builtin_amdgcn_s_barrier();
    if (t + 2 < nt) {
      int sb = cur + 2; if (sb >= 3) sb -= 3;
      stage(t + 2, sb);
    }
    const char* sbuf = smem + cur * BUFB;
    bf16x8 a[4], b[4];
#pragma unroll
    for (int i = 0; i < 4; ++i) a[i] = *(const bf16x8*)(sbuf + aoff[i]);
#pragma unroll
    for (int i = 0; i < 4; ++i) b[i] = *(const bf16x8*)(sbuf + boff[i]);
#pragma unroll
    for (int i = 0; i < 4; ++i)
#pragma unroll
      for (int j = 0; j < 4; ++j)
        acc[i][j] = __builtin_amdgcn_mfma_f32_16x16x32_bf16(a[i], b[j], acc[i][j], 0, 0, 0);
    cur = cur + 1; if (cur >= 3) cur -= 3;
  }

  if (Vt && n0 >= vthresh) {
    // transposed V output: acc -> LDS [BN col][BM row] bf16 (swizzled), then
    // coalesced 128B row-segment writes to Vt[(n0-vthresh+col)][m0..m0+BM)
    static_assert(BN * BM * 2 <= 3 * BUFB, "LDS too small for V transpose");
    __syncthreads();
#pragma unroll
    for (int tm = 0; tm < 4; ++tm) {
#pragma unroll
      for (int tn = 0; tn < 4; ++tn) {
        const int col = wn * 64 + tn * 16 + fr;
        const int rowb = wm * 64 + tm * 16 + fg * 4;
        bf16x4 o;
#pragma unroll
        for (int i = 0; i < 4; ++i) o[i] = (__bf16)(acc[tm][tn][i] * scale);
        *(bf16x4*)(smem + col * (BM * 2) + ((rowb * 2) ^ ((col & 7) << 4))) = o;
      }
    }
    __syncthreads();
    constexpr int CHUNKS = BM * 2 / 16;          // 16B chunks per column
    constexpr int COLS_PER_REP = (NW * 64) / CHUNKS;
    const int k = tid % CHUNKS;
#pragma unroll
    for (int rep = 0; rep < BN / COLS_PER_REP; ++rep) {
      const int col = (tid / CHUNKS) + rep * COLS_PER_REP;
      bf16x8 v = *(const bf16x8*)(smem + col * (BM * 2) + ((k * 16) ^ ((col & 7) << 4)));
      *(bf16x8*)(Vt + (n0 - vthresh + col) * (long)S_ + m0 + k * 8) = v;
    }
    return;
  }

#pragma unroll
  for (int tm = 0; tm < 4; ++tm) {
#pragma unroll
    for (int tn = 0; tn < 4; ++tn) {
      const long col = n0 + wn * 64 + tn * 16 + fr;
#pragma unroll
      for (int i = 0; i < 4; ++i) {
        const long row = m0 + wm * 64 + tm * 16 + fg * 4 + i;
        float v = acc[tm][tn][i] * scale;
        if (bias) v += bias[col];
        if (relu) v = v > 0.f ? v : 0.f;
        if (resid) v += resid[row * ldc + col];
        if (Cf) Cf[row * ldc + col] = v;
        if (Cb) Cb[row * ldcb + col] = (__bf16)v;
      }
    }
  }
}

// ---------------- in-block split-K NT GEMM (R8, + setprio) ----------------
__global__ __launch_bounds__(256, 2) void gemm_ksplit(
    const bf16* __restrict__ A, const bf16* __restrict__ B,
    long lda, long ldb, int K, int mtiles, float scale,
    const float* __restrict__ bias, const float* __restrict__ resid, int relu,
    float* __restrict__ Cf, long ldc, bf16* __restrict__ Cb, long ldcb) {
  __shared__ char smem[4 * 16384];

  const int tid = threadIdx.x, w = tid >> 6, lane = tid & 63;
  const int cpx = gridDim.x >> 3;
  const int bid = blockIdx.x;
  const int wg = (bid & 7) * cpx + (bid >> 3);
  const long m0 = (long)(wg % mtiles) * 64;
  const long n0 = (long)(wg / mtiles) * 64;
  const int Kq = K >> 2;
  const long k0w = (long)w * Kq;

  const char* gsrc[8];
  int ldsoff[8];
#pragma unroll
  for (int i = 0; i < 8; ++i) {
    const int s = (i & 3) * 1024 + lane * 16;
    const int row = s >> 6;
    const int kb = (s ^ ((row & 3) << 4)) & 63;
    const bf16* base = (i < 4) ? (A + (m0 + row) * lda + k0w)
                               : (B + (n0 + row) * ldb + k0w);
    gsrc[i] = (const char*)base + kb;
    ldsoff[i] = w * 16384 + i * 1024;
  }

  const int fr = lane & 15, fg = lane >> 4;
  int aoff[4], boff[4];
#pragma unroll
  for (int t = 0; t < 4; ++t) {
    const int m = t * 16 + fr;
    aoff[t] = w * 16384 + m * 64 + ((16 * fg) ^ ((m & 3) << 4));
    boff[t] = aoff[t] + 4096;
  }

  f32x4 acc[4][4];
#pragma unroll
  for (int i = 0; i < 4; ++i)
#pragma unroll
    for (int j = 0; j < 4; ++j) acc[i][j] = (f32x4){0.f, 0.f, 0.f, 0.f};

  const int nt = Kq >> 5;

  auto stage = [&](int tile, int buf) {
    const long koff = (long)tile * 64;
#pragma unroll
    for (int i = 0; i < 8; ++i)
      gld16(gsrc[i] + koff, smem + ldsoff[i] + buf * 8192);
  };

  stage(0, 0);
  if (nt > 1) stage(1, 1);

  for (int t = 0; t < nt; ++t) {
    if (t + 1 < nt) asm volatile("s_waitcnt vmcnt(8)" ::: "memory");
    else asm volatile("s_waitcnt vmcnt(0)" ::: "memory");
    const int bsel = (t & 1) * 8192;
    bf16x8 a[4], b[4];
#pragma unroll
    for (int i = 0; i < 4; ++i) a[i] = *(const bf16x8*)(smem + aoff[i] + bsel);
#pragma unroll
    for (int i = 0; i < 4; ++i) b[i] = *(const bf16x8*)(smem + boff[i] + bsel);
    __builtin_amdgcn_s_setprio(1);
#pragma unroll
    for (int i = 0; i < 4; ++i)
#pragma unroll
      for (int j = 0; j < 4; ++j)
        acc[i][j] = __builtin_amdgcn_mfma_f32_16x16x32_bf16(a[i], b[j], acc[i][j], 0, 0, 0);
    __builtin_amdgcn_s_setprio(0);
    if (t + 2 < nt) stage(t + 2, t & 1);
  }

  __syncthreads();
#pragma unroll
  for (int f = 0; f < 16; ++f)
    *(f32x4*)(smem + w * 16384 + f * 1024 + lane * 16) = acc[f >> 2][f & 3];
  __syncthreads();

#pragma unroll
  for (int tn = 0; tn < 4; ++tn) {
    const int f = w * 4 + tn;
    f32x4 v0 = *(const f32x4*)(smem + 0 * 16384 + f * 1024 + lane * 16);
    f32x4 v1 = *(const f32x4*)(smem + 1 * 16384 + f * 1024 + lane * 16);
    f32x4 v2 = *(const f32x4*)(smem + 2 * 16384 + f * 1024 + lane * 16);
    f32x4 v3 = *(const f32x4*)(smem + 3 * 16384 + f * 1024 + lane * 16);
    f32x4 sv;
#pragma unroll
    for (int i = 0; i < 4; ++i) sv[i] = v0[i] + v1[i] + v2[i] + v3[i];
    const long col = n0 + tn * 16 + fr;
#pragma unroll
    for (int i = 0; i < 4; ++i) {
      const long row = m0 + w * 16 + fg * 4 + i;
      float v = sv[i] * scale;
      if (bias) v += bias[col];
      if (relu) v = v > 0.f ? v : 0.f;
      if (resid) v += resid[row * ldc + col];
      if (Cf) Cf[row * ldc + col] = v;
      if (Cb) Cb[row * ldcb + col] = (__bf16)v;
    }
  }
}

// ---------------- fused two-pass attention, barrier-free (R10) ----------------
__global__ __launch_bounds__(256, 2) void attn_fused(
    const bf16* __restrict__ qkv,  // [S][3E] (Q at 0, K at E; V cols unused)
    const bf16* __restrict__ vt,   // [E][S]
    float* __restrict__ att,       // [H][S][S]
    bf16* __restrict__ avb) {      // [S][E]
  constexpr int QB = 64, KB = 128;
  constexpr int NKT = S_ / KB;
  constexpr float C2 = 0.1803368801111244f;  // 0.125 * log2(e)
  __shared__ char plds[QB * 256];

  const int tid = threadIdx.x, lane = tid & 63, w = tid >> 6;
  const int fr = lane & 15, fg = lane >> 4;
  const int bid = blockIdx.x;
  const int wg = (bid & 7) * 64 + (bid >> 3);
  const int h = wg >> 5;
  const long q0 = (long)(wg & 31) * QB;
  const int q = w * 16 + fr;
  const int swz = (q & 15) << 4;

  bf16x8 qf[2];
#pragma unroll
  for (int k0 = 0; k0 < 2; ++k0)
    qf[k0] = *(const bf16x8*)(qkv + (q0 + q) * (3 * E_) + h * HS_ + k0 * 32 + fg * 8);

  float l_ = 0.f;

  for (int kt = 0; kt < NKT; ++kt) {
    const long t0 = (long)kt * KB;
    bf16x8 kf[8][2];
#pragma unroll
    for (int mt = 0; mt < 8; ++mt)
#pragma unroll
      for (int k0 = 0; k0 < 2; ++k0)
        kf[mt][k0] = *(const bf16x8*)(qkv + (t0 + mt * 16 + fr) * (3 * E_) +
                                      E_ + h * HS_ + k0 * 32 + fg * 8);
    f32x4 acc[8];
#pragma unroll
    for (int mt = 0; mt < 8; ++mt) acc[mt] = (f32x4){0.f, 0.f, 0.f, 0.f};
    __builtin_amdgcn_s_setprio(1);
#pragma unroll
    for (int k0 = 0; k0 < 2; ++k0)
#pragma unroll
      for (int mt = 0; mt < 8; ++mt)
        acc[mt] = __builtin_amdgcn_mfma_f32_16x16x32_bf16(kf[mt][k0], qf[k0], acc[mt], 0, 0, 0);
    __builtin_amdgcn_s_setprio(0);
    float sum = 0.f;
#pragma unroll
    for (int mt = 0; mt < 8; ++mt)
#pragma unroll
      for (int i = 0; i < 4; ++i) sum += __builtin_amdgcn_exp2f(acc[mt][i] * C2);
    l_ += sum;
  }
  l_ += __shfl_xor(l_, 16);
  l_ += __shfl_xor(l_, 32);
  const float li = -__log2f(l_);

  f32x4 ao[4];
#pragma unroll
  for (int d = 0; d < 4; ++d) ao[d] = (f32x4){0.f, 0.f, 0.f, 0.f};

  for (int kt = 0; kt < NKT; ++kt) {
    const long t0 = (long)kt * KB;
    bf16x8 kf[8][2];
#pragma unroll
    for (int mt = 0; mt < 8; ++mt)
#pragma unroll
      for (int k0 = 0; k0 < 2; ++k0)
        kf[mt][k0] = *(const bf16x8*)(qkv + (t0 + mt * 16 + fr) * (3 * E_) +
                                      E_ + h * HS_ + k0 * 32 + fg * 8);
    f32x4 acc[8];
#pragma unroll
    for (int mt = 0; mt < 8; ++mt) acc[mt] = (f32x4){0.f, 0.f, 0.f, 0.f};
    __builtin_amdgcn_s_setprio(1);
#pragma unroll
    for (int k0 = 0; k0 < 2; ++k0)
#pragma unroll
      for (int mt = 0; mt < 8; ++mt)
        acc[mt] = __builtin_amdgcn_mfma_f32_16x16x32_bf16(kf[mt][k0], qf[k0], acc[mt], 0, 0, 0);
    __builtin_amdgcn_s_setprio(0);

    float* arow = att + ((long)h * S_ + q0 + q) * S_ + t0;
#pragma unroll
    for (int mt = 0; mt < 8; ++mt) {
      f32x4 pv;
#pragma unroll
      for (int i = 0; i < 4; ++i)
        pv[i] = __builtin_amdgcn_exp2f(fmaf(acc[mt][i], C2, li));
      __builtin_nontemporal_store(pv, (f32x4*)(arow + mt * 16 + fg * 4));
      bf16x4 pb;
      pb[0] = (__bf16)pv[0]; pb[1] = (__bf16)pv[1];
      pb[2] = (__bf16)pv[2]; pb[3] = (__bf16)pv[3];
      const int tb = (mt * 16 + fg * 4) * 2;
      *(bf16x4*)(plds + q * 256 + ((tb & ~15) ^ swz) + (tb & 15)) = pb;
    }

#pragma unroll
    for (int k0 = 0; k0 < 4; ++k0) {
      const bf16x8 bq = *(const bf16x8*)(plds + q * 256 + ((k0 * 64 + fg * 16) ^ swz));
      __builtin_amdgcn_s_setprio(1);
#pragma unroll
      for (int dmt = 0; dmt < 4; ++dmt) {
        bf16x8 av = *(const bf16x8*)(vt + (long)(h * HS_ + dmt * 16 + fr) * S_ +
                                     t0 + k0 * 32 + fg * 8);
        ao[dmt] = __builtin_amdgcn_mfma_f32_16x16x32_bf16(av, bq, ao[dmt], 0, 0, 0);
      }
      __builtin_amdgcn_s_setprio(0);
    }
  }

#pragma unroll
  for (int dmt = 0; dmt < 4; ++dmt) {
    bf16x4 o;
    o[0] = (__bf16)ao[dmt][0]; o[1] = (__bf16)ao[dmt][1];
    o[2] = (__bf16)ao[dmt][2]; o[3] = (__bf16)ao[dmt][3];
    *(bf16x4*)(avb + (q0 + q) * E_ + h * HS_ + dmt * 16 + fg * 4) = o;
  }
}

extern "C" void kernel_launch(void* const* d_in, const int* in_sizes, int n_in,
                              void* d_out, int out_size, void* d_ws, size_t ws_size,
                              hipStream_t stream) {
  const int* seq = (const int*)d_in[0];
  const float* tok_emb = (const float*)d_in[1];
  const float* pos_emb = (const float*)d_in[2];
  const float* Wq = (const float*)d_in[3];
  const float* Wk = (const float*)d_in[4];
  const float* Wv = (const float*)d_in[5];
  const float* Wr = (const float*)d_in[6];
  const float* br = (const float*)d_in[7];
  const float* W1 = (const float*)d_in[8];
  const float* b1 = (const float*)d_in[9];
  const float* W2 = (const float*)d_in[10];
  const float* b2 = (const float*)d_in[11];
  const float* ln_g = (const float*)d_in[12];
  const float* ln_b = (const float*)d_in[13];

  float* outx = (float*)d_out;
  float* att_all = outx + (long)S_ * E_;

  char* w = (char*)d_ws;
  auto alloc = [&](size_t bytes) {
    char* p = w;
    w += (bytes + 255) & ~(size_t)255;
    return p;
  };
  float* x = (float*)alloc((size_t)S_ * E_ * 4);
  bf16* xb = (bf16*)alloc((size_t)S_ * E_ * 2);
  bf16* qkvb = (bf16*)alloc((size_t)S_ * 3 * E_ * 2);
  bf16* vt = (bf16*)alloc((size_t)E_ * S_ * 2);
  bf16* avb = (bf16*)alloc((size_t)S_ * E_ * 2);
  bf16* hb = (bf16*)alloc((size_t)S_ * FF_ * 2);
  bf16* wqkvT = (bf16*)alloc((size_t)3 * E_ * E_ * 2);
  bf16* wrT = (bf16*)alloc((size_t)E_ * E_ * 2);
  bf16* w1T = (bf16*)alloc((size_t)E_ * FF_ * 2);
  bf16* w2T = (bf16*)alloc((size_t)E_ * FF_ * 2);
  (void)ws_size; (void)in_sizes; (void)n_in; (void)out_size;

  embed_ln_k<<<S_, 256, 0, stream>>>(seq, tok_emb, pos_emb, ln_g, ln_b, x, xb);

  for (int l = 0; l < L_; ++l) {
    repack_k<<<12288, dim3(32, 8, 1), 0, stream>>>(
        Wq + (long)l * H_ * E_ * HS_, Wk + (long)l * H_ * E_ * HS_,
        Wv + (long)l * H_ * E_ * HS_, Wr + (long)l * E_ * E_,
        W1 + (long)l * E_ * FF_, W2 + (long)l * FF_ * E_,
        wqkvT, wrT, w1T, w2T);

    if (l > 0)
      layernorm_k<<<S_, 256, 0, stream>>>(x, ln_g + (long)l * E_, ln_b + (long)l * E_, xb);

    // qkv = xb @ WqkvT^T; V-blocks (n0 >= 2E) write transposed into vt directly
    gemm_lds<1, 2><<<768, 128, 0, stream>>>(
        xb, wqkvT, E_, E_, E_, 32, 1.f, nullptr, nullptr, 0,
        nullptr, 0, qkvb, 3 * E_, vt, 2 * E_);

    float* att_l = att_all + (long)l * H_ * S_ * S_;
    attn_fused<<<512, 256, 0, stream>>>(qkvb, vt, att_l, avb);

    // x = x + avb @ WrT^T + br   (split-K)
    gemm_ksplit<<<32 * 16, 256, 0, stream>>>(
        avb, wrT, E_, E_, E_, 32, 1.f, br + (long)l * E_, x, 0,
        x, E_, nullptr, 0);

    layernorm_k<<<S_, 256, 0, stream>>>(x, ln_g + (long)l * E_, ln_b + (long)l * E_, xb);

    // hb = relu(xb @ W1T^T + b1)   (<1,2> @1024 blocks = 4/CU exact)
    gemm_lds<1, 2><<<1024, 128, 0, stream>>>(
        xb, w1T, E_, E_, E_, 32, 1.f, b1 + (long)l * FF_, nullptr, 1,
        nullptr, 0, hb, FF_, nullptr, 0x7fffffffL);

    // x = x + hb @ W2T^T + b2   (split-K; last layer -> d_out)
    float* xdst = (l == L_ - 1) ? outx : x;
    gemm_ksplit<<<32 * 16, 256, 0, stream>>>(
        hb, w2T, FF_, FF_, FF_, 32, 1.f, b2 + (long)l * E_, x, 0,
        xdst, E_, nullptr, 0);
  }
}

// Round 12
// 684.720 us; speedup vs baseline: 1.0225x; 1.0225x over previous
//
#include <hip/hip_runtime.h>
#include <hip/hip_bf16.h>

// Round 12: R10 base (best: 691.8). New: fat-kernel overlap — repack(l=0) rides
// inside the embed launch; repack(l=1) rides inside attn(l=0) with double-buffered
// weight sets (runtime ws_size check, serial fallback). Everything else = R10.

constexpr int S_ = 2048;
constexpr int E_ = 1024;
constexpr int H_ = 16;
constexpr int HS_ = 64;
constexpr int L_ = 2;
constexpr int FF_ = 4096;

typedef __bf16 bf16;
typedef __bf16 bf16x8 __attribute__((ext_vector_type(8)));
typedef __bf16 bf16x4 __attribute__((ext_vector_type(4)));
typedef float f32x4 __attribute__((ext_vector_type(4)));

__device__ __forceinline__ void gld16(const void* g, const void* l) {
  __builtin_amdgcn_global_load_lds(
      (const __attribute__((address_space(1))) unsigned int*)g,
      (__attribute__((address_space(3))) unsigned int*)l, 16, 0, 0);
}

// ---------------- repack tile body (bid in [0,12288)) ----------------
__device__ __forceinline__ void repack_tile(int bid, int tid,
                                            const float* __restrict__ wq,
                                            const float* __restrict__ wk,
                                            const float* __restrict__ wv,
                                            const float* __restrict__ wr,
                                            const float* __restrict__ w1,
                                            const float* __restrict__ w2,
                                            bf16* __restrict__ qkvT,
                                            bf16* __restrict__ wrT,
                                            bf16* __restrict__ w1T,
                                            bf16* __restrict__ w2T,
                                            float (*t)[33]) {
  const int tx = tid & 31, ty = tid >> 5;
  const float* src;
  bf16* dst;
  long ld_in, ld_out, r0, c0;
  if (bid < 3072) {
    const int j = bid >> 10;
    const int z = (bid & 1023) >> 6;
    const int rem = bid & 63;
    r0 = (rem >> 1) * 32;
    c0 = (rem & 1) * 32;
    const float* w = j == 0 ? wq : (j == 1 ? wk : wv);
    src = w + (long)z * E_ * HS_;
    dst = qkvT + (long)j * E_ * E_ + (long)z * HS_ * E_;
    ld_in = HS_; ld_out = E_;
  } else if (bid < 4096) {
    const int idx = bid - 3072;
    r0 = (idx >> 5) * 32; c0 = (idx & 31) * 32;
    src = wr; dst = wrT; ld_in = E_; ld_out = E_;
  } else if (bid < 8192) {
    const int idx = bid - 4096;
    r0 = (idx >> 7) * 32; c0 = (idx & 127) * 32;
    src = w1; dst = w1T; ld_in = FF_; ld_out = E_;
  } else {
    const int idx = bid - 8192;
    r0 = (idx >> 5) * 32; c0 = (idx & 31) * 32;
    src = w2; dst = w2T; ld_in = E_; ld_out = FF_;
  }
#pragma unroll
  for (int i = 0; i < 4; ++i)
    t[ty + 8 * i][tx] = src[(r0 + ty + 8 * i) * ld_in + c0 + tx];
  __syncthreads();
#pragma unroll
  for (int i = 0; i < 4; ++i)
    dst[(c0 + ty + 8 * i) * ld_out + r0 + tx] = (__bf16)t[tx][ty + 8 * i];
}

// ---------------- embedding + first LN, with repack(l=0) riding along ----------------
__global__ __launch_bounds__(256) void embed_ln_repack_k(
    const int* __restrict__ seq, const float* __restrict__ tok,
    const float* __restrict__ pos, const float* __restrict__ gw,
    const float* __restrict__ bw, float* __restrict__ x, bf16* __restrict__ xb,
    const float* wq, const float* wk, const float* wv, const float* wr,
    const float* w1, const float* w2,
    bf16* qkvT, bf16* wrT, bf16* w1T, bf16* w2T) {
  __shared__ float red[8];
  __shared__ float t[32][33];
  const int tid = threadIdx.x;
  if (blockIdx.x >= S_) {
    repack_tile(blockIdx.x - S_, tid, wq, wk, wv, wr, w1, w2,
                qkvT, wrT, w1T, w2T, t);
    return;
  }
  const int row = blockIdx.x;
  const int tk = seq[row];
  float4 v = ((const float4*)(tok + (long)tk * E_))[tid];
  float4 p = ((const float4*)(pos + (long)row * E_))[tid];
  v.x += p.x; v.y += p.y; v.z += p.z; v.w += p.w;
  float s = v.x + v.y + v.z + v.w;
  float ss = v.x * v.x + v.y * v.y + v.z * v.z + v.w * v.w;
  for (int off = 32; off; off >>= 1) {
    s += __shfl_down(s, off);
    ss += __shfl_down(ss, off);
  }
  if ((tid & 63) == 0) { red[(tid >> 6) * 2] = s; red[(tid >> 6) * 2 + 1] = ss; }
  __syncthreads();
  if (tid == 0) {
    float S0 = 0, SS = 0;
    for (int i = 0; i < 4; ++i) { S0 += red[i * 2]; SS += red[i * 2 + 1]; }
    red[0] = S0; red[1] = SS;
  }
  __syncthreads();
  const float mu = red[0] * (1.f / E_);
  const float var = red[1] * (1.f / E_) - mu * mu;
  const float rs = rsqrtf(var + 1e-5f);
  float4 gv = ((const float4*)gw)[tid], bv = ((const float4*)bw)[tid];
  float4 o;
  o.x = (v.x - mu) * rs * gv.x + bv.x;
  o.y = (v.y - mu) * rs * gv.y + bv.y;
  o.z = (v.z - mu) * rs * gv.z + bv.z;
  o.w = (v.w - mu) * rs * gv.w + bv.w;
  ((float4*)(x + (long)row * E_))[tid] = o;
  bf16x4 ob;
  ob[0] = (__bf16)o.x; ob[1] = (__bf16)o.y; ob[2] = (__bf16)o.z; ob[3] = (__bf16)o.w;
  ((bf16x4*)(xb + (long)row * E_))[tid] = ob;
}

// ---------------- layernorm (in-place f32) + bf16 shadow ----------------
__global__ __launch_bounds__(256) void layernorm_k(float* __restrict__ x,
                                                   const float* __restrict__ gw,
                                                   const float* __restrict__ bw,
                                                   bf16* __restrict__ xb) {
  __shared__ float red[8];
  const int row = blockIdx.x, tid = threadIdx.x;
  float4 v = ((const float4*)(x + (long)row * E_))[tid];
  float s = v.x + v.y + v.z + v.w;
  float ss = v.x * v.x + v.y * v.y + v.z * v.z + v.w * v.w;
  for (int off = 32; off; off >>= 1) {
    s += __shfl_down(s, off);
    ss += __shfl_down(ss, off);
  }
  if ((tid & 63) == 0) { red[(tid >> 6) * 2] = s; red[(tid >> 6) * 2 + 1] = ss; }
  __syncthreads();
  if (tid == 0) {
    float S0 = 0, SS = 0;
    for (int i = 0; i < 4; ++i) { S0 += red[i * 2]; SS += red[i * 2 + 1]; }
    red[0] = S0; red[1] = SS;
  }
  __syncthreads();
  const float mu = red[0] * (1.f / E_);
  const float var = red[1] * (1.f / E_) - mu * mu;
  const float rs = rsqrtf(var + 1e-5f);
  float4 gv = ((const float4*)gw)[tid], bv = ((const float4*)bw)[tid];
  float4 o;
  o.x = (v.x - mu) * rs * gv.x + bv.x;
  o.y = (v.y - mu) * rs * gv.y + bv.y;
  o.z = (v.z - mu) * rs * gv.z + bv.z;
  o.w = (v.w - mu) * rs * gv.w + bv.w;
  ((float4*)(x + (long)row * E_))[tid] = o;
  bf16x4 ob;
  ob[0] = (__bf16)o.x; ob[1] = (__bf16)o.y; ob[2] = (__bf16)o.z; ob[3] = (__bf16)o.w;
  ((bf16x4*)(xb + (long)row * E_))[tid] = ob;
}

// ---------------- standalone repack ----------------
__global__ __launch_bounds__(256) void repack_k(const float* wq, const float* wk,
                                                const float* wv, const float* wr,
                                                const float* w1, const float* w2,
                                                bf16* qkvT, bf16* wrT,
                                                bf16* w1T, bf16* w2T) {
  __shared__ float t[32][33];
  repack_tile(blockIdx.x, threadIdx.x, wq, wk, wv, wr, w1, w2,
              qkvT, wrT, w1T, w2T, t);
}

// ---------------- bf16 transpose for V^T ----------------
__global__ __launch_bounds__(256) void trans_b2b(const bf16* __restrict__ in,
                                                 bf16* __restrict__ out,
                                                 long ld_in, long ld_out) {
  __shared__ bf16 t[32][33];
  const int tx = threadIdx.x, ty = threadIdx.y;
  const long r0 = (long)blockIdx.x * 32, c0 = (long)blockIdx.y * 32;
#pragma unroll
  for (int i = 0; i < 4; ++i)
    t[ty + 8 * i][tx] = in[(r0 + ty + 8 * i) * ld_in + c0 + tx];
  __syncthreads();
#pragma unroll
  for (int i = 0; i < 4; ++i)
    out[(c0 + ty + 8 * i) * ld_out + r0 + tx] = t[tx][ty + 8 * i];
}

// ---------------- 3-buffer counted-vmcnt NT GEMM (shared staging, barrier) ----------------
template <int WM, int WN>
__global__ __launch_bounds__(WM * WN * 64) void gemm_lds(
    const bf16* __restrict__ A, const bf16* __restrict__ B,
    long lda, long ldb, int K, int mtiles, float scale,
    const float* __restrict__ bias, const float* __restrict__ resid, int relu,
    float* __restrict__ Cf, long ldc, bf16* __restrict__ Cb, long ldcb) {
  constexpr int BM = WM * 64, BN = WN * 64, NW = WM * WN;
  constexpr int ABYTES = BM * 64;
  constexpr int BUFB = ABYTES + BN * 64;
  constexpr int NCH = BUFB / 1024;
  constexpr int CPT = NCH / NW;
  static_assert(CPT == 4 || CPT == 6, "unexpected CPT");
  __shared__ char smem[3 * BUFB];

  const int tid = threadIdx.x, wid = tid >> 6, lane = tid & 63;
  const int cpx = gridDim.x >> 3;
  const int bid = blockIdx.x;
  const int wg = (bid & 7) * cpx + (bid >> 3);
  const long m0 = (long)(wg % mtiles) * BM;
  const long n0 = (long)(wg / mtiles) * BN;

  const char* gsrc[CPT];
  int ldsbase[CPT];
#pragma unroll
  for (int i = 0; i < CPT; ++i) {
    const int c = wid + i * NW;
    const int s = c * 1024 + lane * 16;
    const bf16* base;
    int kb;
    if (s < ABYTES) {
      const int row = s >> 6;
      kb = (s ^ ((row & 3) << 4)) & 63;
      base = A + (m0 + row) * lda;
    } else {
      const int s2 = s - ABYTES;
      const int row = s2 >> 6;
      kb = (s2 ^ ((row & 3) << 4)) & 63;
      base = B + (n0 + row) * ldb;
    }
    gsrc[i] = (const char*)base + kb;
    ldsbase[i] = c * 1024;
  }

  const int fr = lane & 15, fg = lane >> 4;
  const int wm = wid % WM, wn = wid / WM;
  int aoff[4], boff[4];
#pragma unroll
  for (int t = 0; t < 4; ++t) {
    const int m = wm * 64 + t * 16 + fr;
    aoff[t] = m * 64 + ((16 * fg) ^ ((m & 3) << 4));
    const int n = wn * 64 + t * 16 + fr;
    boff[t] = ABYTES + n * 64 + ((16 * fg) ^ ((n & 3) << 4));
  }

  f32x4 acc[4][4];
#pragma unroll
  for (int i = 0; i < 4; ++i)
#pragma unroll
    for (int j = 0; j < 4; ++j) acc[i][j] = (f32x4){0.f, 0.f, 0.f, 0.f};

  const int nt = K >> 5;

  auto stage = [&](int tile, int buf) {
    const long koff = (long)tile * 64;
#pragma unroll
    for (int i = 0; i < CPT; ++i)
      gld16(gsrc[i] + koff, smem + buf * BUFB + ldsbase[i]);
  };

  stage(0, 0);
  stage(1, 1);

  int cur = 0;
  for (int t = 0; t < nt; ++t) {
    if (t < nt - 1) {
      if constexpr (CPT == 4) asm volatile("s_waitcnt vmcnt(4)" ::: "memory");
      else asm volatile("s_waitcnt vmcnt(6)" ::: "memory");
    } else {
      asm volatile("s_waitcnt vmcnt(0)" ::: "memory");
    }
    __builtin_amdgcn_s_barrier();
    if (t + 2 < nt) {
      int sb = cur + 2; if (sb >= 3) sb -= 3;
      stage(t + 2, sb);
    }
    const char* sbuf = smem + cur * BUFB;
    bf16x8 a[4], b[4];
#pragma unroll
    for (int i = 0; i < 4; ++i) a[i] = *(const bf16x8*)(sbuf + aoff[i]);
#pragma unroll
    for (int i = 0; i < 4; ++i) b[i] = *(const bf16x8*)(sbuf + boff[i]);
#pragma unroll
    for (int i = 0; i < 4; ++i)
#pragma unroll
      for (int j = 0; j < 4; ++j)
        acc[i][j] = __builtin_amdgcn_mfma_f32_16x16x32_bf16(a[i], b[j], acc[i][j], 0, 0, 0);
    cur = cur + 1; if (cur >= 3) cur -= 3;
  }

#pragma unroll
  for (int tm = 0; tm < 4; ++tm) {
#pragma unroll
    for (int tn = 0; tn < 4; ++tn) {
      const long col = n0 + wn * 64 + tn * 16 + fr;
#pragma unroll
      for (int i = 0; i < 4; ++i) {
        const long row = m0 + wm * 64 + tm * 16 + fg * 4 + i;
        float v = acc[tm][tn][i] * scale;
        if (bias) v += bias[col];
        if (relu) v = v > 0.f ? v : 0.f;
        if (resid) v += resid[row * ldc + col];
        if (Cf) Cf[row * ldc + col] = v;
        if (Cb) Cb[row * ldcb + col] = (__bf16)v;
      }
    }
  }
}

// ---------------- in-block split-K NT GEMM (R8, + setprio) ----------------
__global__ __launch_bounds__(256, 2) void gemm_ksplit(
    const bf16* __restrict__ A, const bf16* __restrict__ B,
    long lda, long ldb, int K, int mtiles, float scale,
    const float* __restrict__ bias, const float* __restrict__ resid, int relu,
    float* __restrict__ Cf, long ldc, bf16* __restrict__ Cb, long ldcb) {
  __shared__ char smem[4 * 16384];

  const int tid = threadIdx.x, w = tid >> 6, lane = tid & 63;
  const int cpx = gridDim.x >> 3;
  const int bid = blockIdx.x;
  const int wg = (bid & 7) * cpx + (bid >> 3);
  const long m0 = (long)(wg % mtiles) * 64;
  const long n0 = (long)(wg / mtiles) * 64;
  const int Kq = K >> 2;
  const long k0w = (long)w * Kq;

  const char* gsrc[8];
  int ldsoff[8];
#pragma unroll
  for (int i = 0; i < 8; ++i) {
    const int s = (i & 3) * 1024 + lane * 16;
    const int row = s >> 6;
    const int kb = (s ^ ((row & 3) << 4)) & 63;
    const bf16* base = (i < 4) ? (A + (m0 + row) * lda + k0w)
                               : (B + (n0 + row) * ldb + k0w);
    gsrc[i] = (const char*)base + kb;
    ldsoff[i] = w * 16384 + i * 1024;
  }

  const int fr = lane & 15, fg = lane >> 4;
  int aoff[4], boff[4];
#pragma unroll
  for (int t = 0; t < 4; ++t) {
    const int m = t * 16 + fr;
    aoff[t] = w * 16384 + m * 64 + ((16 * fg) ^ ((m & 3) << 4));
    boff[t] = aoff[t] + 4096;
  }

  f32x4 acc[4][4];
#pragma unroll
  for (int i = 0; i < 4; ++i)
#pragma unroll
    for (int j = 0; j < 4; ++j) acc[i][j] = (f32x4){0.f, 0.f, 0.f, 0.f};

  const int nt = Kq >> 5;

  auto stage = [&](int tile, int buf) {
    const long koff = (long)tile * 64;
#pragma unroll
    for (int i = 0; i < 8; ++i)
      gld16(gsrc[i] + koff, smem + ldsoff[i] + buf * 8192);
  };

  stage(0, 0);
  if (nt > 1) stage(1, 1);

  for (int t = 0; t < nt; ++t) {
    if (t + 1 < nt) asm volatile("s_waitcnt vmcnt(8)" ::: "memory");
    else asm volatile("s_waitcnt vmcnt(0)" ::: "memory");
    const int bsel = (t & 1) * 8192;
    bf16x8 a[4], b[4];
#pragma unroll
    for (int i = 0; i < 4; ++i) a[i] = *(const bf16x8*)(smem + aoff[i] + bsel);
#pragma unroll
    for (int i = 0; i < 4; ++i) b[i] = *(const bf16x8*)(smem + boff[i] + bsel);
    __builtin_amdgcn_s_setprio(1);
#pragma unroll
    for (int i = 0; i < 4; ++i)
#pragma unroll
      for (int j = 0; j < 4; ++j)
        acc[i][j] = __builtin_amdgcn_mfma_f32_16x16x32_bf16(a[i], b[j], acc[i][j], 0, 0, 0);
    __builtin_amdgcn_s_setprio(0);
    if (t + 2 < nt) stage(t + 2, t & 1);
  }

  __syncthreads();
#pragma unroll
  for (int f = 0; f < 16; ++f)
    *(f32x4*)(smem + w * 16384 + f * 1024 + lane * 16) = acc[f >> 2][f & 3];
  __syncthreads();

#pragma unroll
  for (int tn = 0; tn < 4; ++tn) {
    const int f = w * 4 + tn;
    f32x4 v0 = *(const f32x4*)(smem + 0 * 16384 + f * 1024 + lane * 16);
    f32x4 v1 = *(const f32x4*)(smem + 1 * 16384 + f * 1024 + lane * 16);
    f32x4 v2 = *(const f32x4*)(smem + 2 * 16384 + f * 1024 + lane * 16);
    f32x4 v3 = *(const f32x4*)(smem + 3 * 16384 + f * 1024 + lane * 16);
    f32x4 sv;
#pragma unroll
    for (int i = 0; i < 4; ++i) sv[i] = v0[i] + v1[i] + v2[i] + v3[i];
    const long col = n0 + tn * 16 + fr;
#pragma unroll
    for (int i = 0; i < 4; ++i) {
      const long row = m0 + w * 16 + fg * 4 + i;
      float v = sv[i] * scale;
      if (bias) v += bias[col];
      if (relu) v = v > 0.f ? v : 0.f;
      if (resid) v += resid[row * ldc + col];
      if (Cf) Cf[row * ldc + col] = v;
      if (Cb) Cb[row * ldcb + col] = (__bf16)v;
    }
  }
}

// ---------------- attention body (bid in [0,512)) ----------------
__device__ __forceinline__ void attn_body(int bid, int tid,
                                          const bf16* __restrict__ qkv,
                                          const bf16* __restrict__ vt,
                                          float* __restrict__ att,
                                          bf16* __restrict__ avb,
                                          char* plds) {
  constexpr int KB = 128;
  constexpr int NKT = S_ / KB;
  constexpr float C2 = 0.1803368801111244f;  // 0.125 * log2(e)
  const int lane = tid & 63, w = tid >> 6;
  const int fr = lane & 15, fg = lane >> 4;
  const int wg = (bid & 7) * 64 + (bid >> 3);
  const int h = wg >> 5;
  const long q0 = (long)(wg & 31) * 64;
  const int q = w * 16 + fr;
  const int swz = (q & 15) << 4;

  bf16x8 qf[2];
#pragma unroll
  for (int k0 = 0; k0 < 2; ++k0)
    qf[k0] = *(const bf16x8*)(qkv + (q0 + q) * (3 * E_) + h * HS_ + k0 * 32 + fg * 8);

  float l_ = 0.f;

  for (int kt = 0; kt < NKT; ++kt) {
    const long t0 = (long)kt * KB;
    bf16x8 kf[8][2];
#pragma unroll
    for (int mt = 0; mt < 8; ++mt)
#pragma unroll
      for (int k0 = 0; k0 < 2; ++k0)
        kf[mt][k0] = *(const bf16x8*)(qkv + (t0 + mt * 16 + fr) * (3 * E_) +
                                      E_ + h * HS_ + k0 * 32 + fg * 8);
    f32x4 acc[8];
#pragma unroll
    for (int mt = 0; mt < 8; ++mt) acc[mt] = (f32x4){0.f, 0.f, 0.f, 0.f};
    __builtin_amdgcn_s_setprio(1);
#pragma unroll
    for (int k0 = 0; k0 < 2; ++k0)
#pragma unroll
      for (int mt = 0; mt < 8; ++mt)
        acc[mt] = __builtin_amdgcn_mfma_f32_16x16x32_bf16(kf[mt][k0], qf[k0], acc[mt], 0, 0, 0);
    __builtin_amdgcn_s_setprio(0);
    float sum = 0.f;
#pragma unroll
    for (int mt = 0; mt < 8; ++mt)
#pragma unroll
      for (int i = 0; i < 4; ++i) sum += __builtin_amdgcn_exp2f(acc[mt][i] * C2);
    l_ += sum;
  }
  l_ += __shfl_xor(l_, 16);
  l_ += __shfl_xor(l_, 32);
  const float li = -__log2f(l_);

  f32x4 ao[4];
#pragma unroll
  for (int d = 0; d < 4; ++d) ao[d] = (f32x4){0.f, 0.f, 0.f, 0.f};

  for (int kt = 0; kt < NKT; ++kt) {
    const long t0 = (long)kt * KB;
    bf16x8 kf[8][2];
#pragma unroll
    for (int mt = 0; mt < 8; ++mt)
#pragma unroll
      for (int k0 = 0; k0 < 2; ++k0)
        kf[mt][k0] = *(const bf16x8*)(qkv + (t0 + mt * 16 + fr) * (3 * E_) +
                                      E_ + h * HS_ + k0 * 32 + fg * 8);
    f32x4 acc[8];
#pragma unroll
    for (int mt = 0; mt < 8; ++mt) acc[mt] = (f32x4){0.f, 0.f, 0.f, 0.f};
    __builtin_amdgcn_s_setprio(1);
#pragma unroll
    for (int k0 = 0; k0 < 2; ++k0)
#pragma unroll
      for (int mt = 0; mt < 8; ++mt)
        acc[mt] = __builtin_amdgcn_mfma_f32_16x16x32_bf16(kf[mt][k0], qf[k0], acc[mt], 0, 0, 0);
    __builtin_amdgcn_s_setprio(0);

    float* arow = att + ((long)h * S_ + q0 + q) * S_ + t0;
#pragma unroll
    for (int mt = 0; mt < 8; ++mt) {
      f32x4 pv;
#pragma unroll
      for (int i = 0; i < 4; ++i)
        pv[i] = __builtin_amdgcn_exp2f(fmaf(acc[mt][i], C2, li));
      __builtin_nontemporal_store(pv, (f32x4*)(arow + mt * 16 + fg * 4));
      bf16x4 pb;
      pb[0] = (__bf16)pv[0]; pb[1] = (__bf16)pv[1];
      pb[2] = (__bf16)pv[2]; pb[3] = (__bf16)pv[3];
      const int tb = (mt * 16 + fg * 4) * 2;
      *(bf16x4*)(plds + q * 256 + ((tb & ~15) ^ swz) + (tb & 15)) = pb;
    }

#pragma unroll
    for (int k0 = 0; k0 < 4; ++k0) {
      const bf16x8 bq = *(const bf16x8*)(plds + q * 256 + ((k0 * 64 + fg * 16) ^ swz));
      __builtin_amdgcn_s_setprio(1);
#pragma unroll
      for (int dmt = 0; dmt < 4; ++dmt) {
        bf16x8 av = *(const bf16x8*)(vt + (long)(h * HS_ + dmt * 16 + fr) * S_ +
                                     t0 + k0 * 32 + fg * 8);
        ao[dmt] = __builtin_amdgcn_mfma_f32_16x16x32_bf16(av, bq, ao[dmt], 0, 0, 0);
      }
      __builtin_amdgcn_s_setprio(0);
    }
  }

#pragma unroll
  for (int dmt = 0; dmt < 4; ++dmt) {
    bf16x4 o;
    o[0] = (__bf16)ao[dmt][0]; o[1] = (__bf16)ao[dmt][1];
    o[2] = (__bf16)ao[dmt][2]; o[3] = (__bf16)ao[dmt][3];
    *(bf16x4*)(avb + (q0 + q) * E_ + h * HS_ + dmt * 16 + fg * 4) = o;
  }
}

// ---------------- standalone attention ----------------
__global__ __launch_bounds__(256, 2) void attn_fused(
    const bf16* __restrict__ qkv, const bf16* __restrict__ vt,
    float* __restrict__ att, bf16* __restrict__ avb) {
  __shared__ char plds[64 * 256];
  attn_body(blockIdx.x, threadIdx.x, qkv, vt, att, avb, plds);
}

// ---------------- attention + next-layer repack fat kernel ----------------
__global__ __launch_bounds__(256) void attn_repack_k(
    const bf16* __restrict__ qkv, const bf16* __restrict__ vt,
    float* __restrict__ att, bf16* __restrict__ avb,
    const float* wq, const float* wk, const float* wv, const float* wr,
    const float* w1, const float* w2,
    bf16* qkvT, bf16* wrT, bf16* w1T, bf16* w2T) {
  __shared__ char plds[64 * 256];
  __shared__ float t[32][33];
  if (blockIdx.x < 512) {
    attn_body(blockIdx.x, threadIdx.x, qkv, vt, att, avb, plds);
  } else {
    repack_tile(blockIdx.x - 512, threadIdx.x, wq, wk, wv, wr, w1, w2,
                qkvT, wrT, w1T, w2T, t);
  }
}

extern "C" void kernel_launch(void* const* d_in, const int* in_sizes, int n_in,
                              void* d_out, int out_size, void* d_ws, size_t ws_size,
                              hipStream_t stream) {
  const int* seq = (const int*)d_in[0];
  const float* tok_emb = (const float*)d_in[1];
  const float* pos_emb = (const float*)d_in[2];
  const float* Wq = (const float*)d_in[3];
  const float* Wk = (const float*)d_in[4];
  const float* Wv = (const float*)d_in[5];
  const float* Wr = (const float*)d_in[6];
  const float* br = (const float*)d_in[7];
  const float* W1 = (const float*)d_in[8];
  const float* b1 = (const float*)d_in[9];
  const float* W2 = (const float*)d_in[10];
  const float* b2 = (const float*)d_in[11];
  const float* ln_g = (const float*)d_in[12];
  const float* ln_b = (const float*)d_in[13];

  float* outx = (float*)d_out;
  float* att_all = outx + (long)S_ * E_;

  char* w = (char*)d_ws;
  auto alloc = [&](size_t bytes) {
    char* p = w;
    w += (bytes + 255) & ~(size_t)255;
    return p;
  };
  float* x = (float*)alloc((size_t)S_ * E_ * 4);
  bf16* xb = (bf16*)alloc((size_t)S_ * E_ * 2);
  bf16* qkvb = (bf16*)alloc((size_t)S_ * 3 * E_ * 2);
  bf16* vt = (bf16*)alloc((size_t)E_ * S_ * 2);
  bf16* avb = (bf16*)alloc((size_t)S_ * E_ * 2);
  bf16* hb = (bf16*)alloc((size_t)S_ * FF_ * 2);
  // weight set 0
  bf16* qkvT0 = (bf16*)alloc((size_t)3 * E_ * E_ * 2);
  bf16* wrT0 = (bf16*)alloc((size_t)E_ * E_ * 2);
  bf16* w1T0 = (bf16*)alloc((size_t)E_ * FF_ * 2);
  bf16* w2T0 = (bf16*)alloc((size_t)E_ * FF_ * 2);
  // weight set 1 (only if ws allows)
  const size_t wset_bytes =
      (((size_t)3 * E_ * E_ * 2 + 255) & ~(size_t)255) +
      (((size_t)E_ * E_ * 2 + 255) & ~(size_t)255) +
      2 * (((size_t)E_ * FF_ * 2 + 255) & ~(size_t)255);
  const size_t used = (size_t)(w - (char*)d_ws);
  const bool dbl = ws_size >= used + wset_bytes;
  bf16 *qkvT1 = qkvT0, *wrT1 = wrT0, *w1T1 = w1T0, *w2T1 = w2T0;
  if (dbl) {
    qkvT1 = (bf16*)alloc((size_t)3 * E_ * E_ * 2);
    wrT1 = (bf16*)alloc((size_t)E_ * E_ * 2);
    w1T1 = (bf16*)alloc((size_t)E_ * FF_ * 2);
    w2T1 = (bf16*)alloc((size_t)E_ * FF_ * 2);
  }
  (void)in_sizes; (void)n_in; (void)out_size;

  bf16* qkvT[2] = {qkvT0, qkvT1};
  bf16* wrT[2] = {wrT0, wrT1};
  bf16* w1T[2] = {w1T0, w1T1};
  bf16* w2T[2] = {w2T0, w2T1};

  // embed + LN(0) with repack(l=0) riding along
  embed_ln_repack_k<<<S_ + 12288, 256, 0, stream>>>(
      seq, tok_emb, pos_emb, ln_g, ln_b, x, xb,
      Wq, Wk, Wv, Wr, W1, W2, qkvT0, wrT0, w1T0, w2T0);

  for (int l = 0; l < L_; ++l) {
    if (l > 0) {
      if (!dbl)
        repack_k<<<12288, 256, 0, stream>>>(
            Wq + (long)l * H_ * E_ * HS_, Wk + (long)l * H_ * E_ * HS_,
            Wv + (long)l * H_ * E_ * HS_, Wr + (long)l * E_ * E_,
            W1 + (long)l * E_ * FF_, W2 + (long)l * FF_ * E_,
            qkvT[1], wrT[1], w1T[1], w2T[1]);
      layernorm_k<<<S_, 256, 0, stream>>>(x, ln_g + (long)l * E_, ln_b + (long)l * E_, xb);
    }

    // qkv = xb @ WqkvT^T   [S, 3E]  (64x128 tile -> 768 blocks)
    gemm_lds<1, 2><<<768, 128, 0, stream>>>(
        xb, qkvT[l], E_, E_, E_, 32, 1.f, nullptr, nullptr, 0,
        nullptr, 0, qkvb, 3 * E_);

    trans_b2b<<<dim3(S_ / 32, E_ / 32, 1), dim3(32, 8, 1), 0, stream>>>(
        qkvb + 2 * E_, vt, 3 * E_, S_);

    float* att_l = att_all + (long)l * H_ * S_ * S_;
    if (l == 0 && dbl) {
      // attn(l=0) with repack(l=1) riding along
      attn_repack_k<<<512 + 12288, 256, 0, stream>>>(
          qkvb, vt, att_l, avb,
          Wq + (long)H_ * E_ * HS_, Wk + (long)H_ * E_ * HS_,
          Wv + (long)H_ * E_ * HS_, Wr + (long)E_ * E_,
          W1 + (long)E_ * FF_, W2 + (long)FF_ * E_,
          qkvT[1], wrT[1], w1T[1], w2T[1]);
    } else {
      attn_fused<<<512, 256, 0, stream>>>(qkvb, vt, att_l, avb);
    }

    // x = x + avb @ WrT^T + br   (split-K)
    gemm_ksplit<<<32 * 16, 256, 0, stream>>>(
        avb, wrT[l], E_, E_, E_, 32, 1.f, br + (long)l * E_, x, 0,
        x, E_, nullptr, 0);

    layernorm_k<<<S_, 256, 0, stream>>>(x, ln_g + (long)l * E_, ln_b + (long)l * E_, xb);

    // hb = relu(xb @ W1T^T + b1)
    gemm_lds<2, 2><<<dim3(16 * 32), 256, 0, stream>>>(
        xb, w1T[l], E_, E_, E_, 16, 1.f, b1 + (long)l * FF_, nullptr, 1,
        nullptr, 0, hb, FF_);

    // x = x + hb @ W2T^T + b2   (split-K; last layer -> d_out)
    float* xdst = (l == L_ - 1) ? outx : x;
    gemm_ksplit<<<32 * 16, 256, 0, stream>>>(
        hb, w2T[l], FF_, FF_, FF_, 32, 1.f, b2 + (long)l * E_, x, 0,
        xdst, E_, nullptr, 0);
  }
}